// Round 7
// baseline (470.326 us; speedup 1.0000x reference)
//
#include <hip/hip_runtime.h>
#include <hip/hip_bf16.h>

#define DIMV 512
#define HDV  64
#define VSTR 524                          // shorts per Vt row
#define VT_BASE 65536                     // K region: 512 rows x 128 B (XOR-swizzled)
#define SMEM_B (VT_BASE + 64 * VSTR * 2)  // 132,608 B

typedef __bf16 bf16x8_t __attribute__((ext_vector_type(8)));
typedef float f32x4_t __attribute__((ext_vector_type(4)));

union Frag { bf16x8_t v; unsigned short u[8]; unsigned int w[4]; uint2 d[2]; uint4 q; };

static __device__ __forceinline__ unsigned short f2bf(float f) {
  return __builtin_bit_cast(unsigned short, (__bf16)f);
}
static __device__ __forceinline__ float bf2f(unsigned int h) {
  return __builtin_bit_cast(float, h << 16);
}

// Barrier that does NOT drain vmcnt: LDS visibility only; global loads into
// private carrier regs stay in flight across it.
#define BARRIER_NODRAIN() asm volatile("s_waitcnt lgkmcnt(0)\n\ts_barrier" ::: "memory")

__global__ __launch_bounds__(1024, 4)
void lepe_attn_kernel(const float* __restrict__ qkv,
                      const float* __restrict__ lw,
                      const float* __restrict__ lb,
                      float* __restrict__ out)
{
  __shared__ __align__(16) unsigned char smem[SMEM_B];

  const int wb   = blockIdx.x;        // 256 blocks; each does 2 heads of one window
  const int win  = wb >> 2;
  const int bat  = win >> 3;
  const int nw   = win & 7;
  const int headbase = (wb & 3) << 1; // heads {headbase, headbase+1}

  const int tid  = threadIdx.x;
  const int wave = tid >> 6, lane = tid & 63;
  const int l15  = lane & 15, g = lane >> 4;

  const float* qptr = qkv;
  const float* kptr = qkv + 16777216;
  const float* vptr = qkv + 33554432;
  const int rowbase = bat * 4096;

  auto grow = [&](int tok) -> int {   // window token -> global row
    return rowbase + ((tok >> 3) << 6) + (nw << 3) + (tok & 7);
  };

  // ---- staging mapping: token s_t (0..63 within group), channel quad s_c ----
  const int s_t = tid >> 4;
  const int s_c = (tid & 15) * 4;
  const size_t TSTRIDE = 262144;      // floats between consecutive 64-token groups
  const size_t base_st = (size_t)grow(s_t) * DIMV + s_c;

  size_t qoff[2];
  qoff[0] = (size_t)grow(wave * 32 + l15) * DIMV;
  qoff[1] = (size_t)grow(wave * 32 + 16 + l15) * DIMV;

  const int kwbase = s_t * 128 + ((s_c * 2) ^ ((s_t & 7) << 4));
  unsigned short* vt = (unsigned short*)(smem + VT_BASE);

  float4 ck0, ck1, cv0, cv1;   // chunk carrier (2 groups K + 2 groups V)
  float4 qin[8];               // Q carrier

  auto issueC = [&](int head, int c) {
    const float* kgp = kptr + base_st + head * HDV;
    const float* vgp = vptr + base_st + head * HDV;
    ck0 = *(const float4*)(kgp + (size_t)(2 * c) * TSTRIDE);
    ck1 = *(const float4*)(kgp + (size_t)(2 * c + 1) * TSTRIDE);
    cv0 = *(const float4*)(vgp + (size_t)(2 * c) * TSTRIDE);
    cv1 = *(const float4*)(vgp + (size_t)(2 * c + 1) * TSTRIDE);
  };
  auto issueQ = [&](int head) {
    #pragma unroll
    for (int qi = 0; qi < 2; ++qi) {
      const float* qp = qptr + qoff[qi] + head * HDV;
      #pragma unroll
      for (int kc = 0; kc < 2; ++kc) {
        qin[qi * 4 + kc * 2 + 0] = *(const float4*)(qp + kc * 32 + 8 * g);
        qin[qi * 4 + kc * 2 + 1] = *(const float4*)(qp + kc * 32 + 8 * g + 4);
      }
    }
  };
  auto writeC = [&](int c) {
    uint2 kp;
    kp.x = (unsigned)f2bf(ck0.x) | ((unsigned)f2bf(ck0.y) << 16);
    kp.y = (unsigned)f2bf(ck0.z) | ((unsigned)f2bf(ck0.w) << 16);
    *(uint2*)(smem + kwbase + (2 * c) * 8192) = kp;
    kp.x = (unsigned)f2bf(ck1.x) | ((unsigned)f2bf(ck1.y) << 16);
    kp.y = (unsigned)f2bf(ck1.z) | ((unsigned)f2bf(ck1.w) << 16);
    *(uint2*)(smem + kwbase + (2 * c + 1) * 8192) = kp;
    int t0 = s_t + 128 * c;
    vt[(s_c + 0) * VSTR + t0] = f2bf(cv0.x);
    vt[(s_c + 1) * VSTR + t0] = f2bf(cv0.y);
    vt[(s_c + 2) * VSTR + t0] = f2bf(cv0.z);
    vt[(s_c + 3) * VSTR + t0] = f2bf(cv0.w);
    int t1 = t0 + 64;
    vt[(s_c + 0) * VSTR + t1] = f2bf(cv1.x);
    vt[(s_c + 1) * VSTR + t1] = f2bf(cv1.y);
    vt[(s_c + 2) * VSTR + t1] = f2bf(cv1.z);
    vt[(s_c + 3) * VSTR + t1] = f2bf(cv1.w);
  };

  const float QSC = 0.1803368801f;   // 0.125 * log2(e): P = exp2(S)
  Frag qf[2][2];
  auto buildQF = [&]() {
    #pragma unroll
    for (int qi = 0; qi < 2; ++qi)
      #pragma unroll
      for (int kc = 0; kc < 2; ++kc) {
        const float4 f0 = qin[qi * 4 + kc * 2 + 0];
        const float4 f1 = qin[qi * 4 + kc * 2 + 1];
        qf[qi][kc].u[0] = f2bf(f0.x * QSC); qf[qi][kc].u[1] = f2bf(f0.y * QSC);
        qf[qi][kc].u[2] = f2bf(f0.z * QSC); qf[qi][kc].u[3] = f2bf(f0.w * QSC);
        qf[qi][kc].u[4] = f2bf(f1.x * QSC); qf[qi][kc].u[5] = f2bf(f1.y * QSC);
        qf[qi][kc].u[6] = f2bf(f1.z * QSC); qf[qi][kc].u[7] = f2bf(f1.w * QSC);
      }
  };

  // ---- prologue: pair-0 chunk0 + Q in flight; write; publish ----
  issueC(headbase, 0);
  issueQ(headbase);
  writeC(0);
  buildQF();
  BARRIER_NODRAIN();

  const f32x4_t zero4 = {0.f, 0.f, 0.f, 0.f};
  const int ksw = (l15 & 7) << 4;
  const int qbase = wave * 32;

  for (int p = 0; p < 2; ++p) {
    const int head = headbase + p;

    f32x4_t ot[4][2];
    #pragma unroll
    for (int di = 0; di < 4; ++di)
      #pragma unroll
      for (int qi = 0; qi < 2; ++qi) ot[di][qi] = zero4;
    float lsum[2] = {0.f, 0.f};

    // ---- main loop: 4 chunks x 4 tiles of 32 keys; 1-ahead pipeline ----
    #pragma unroll
    for (int c = 0; c < 4; ++c) {
      if (c < 3) issueC(head, c + 1);
      else if (p == 0) issueQ(headbase + 1);   // pair-1 Q under chunk-3 compute

      #pragma unroll
      for (int t4 = 0; t4 < 4; ++t4) {
        const int kt = c * 4 + t4;

        Frag kf[2][2];
        #pragma unroll
        for (int ki = 0; ki < 2; ++ki) {
          const unsigned char* rowp = smem + (kt * 32 + ki * 16 + l15) * 128;
          #pragma unroll
          for (int kc = 0; kc < 2; ++kc)
            kf[ki][kc].q = *(const uint4*)(rowp + ((kc * 64 + g * 16) ^ ksw));
        }

        f32x4_t st[2][2];
        #pragma unroll
        for (int ki = 0; ki < 2; ++ki)
          #pragma unroll
          for (int qi = 0; qi < 2; ++qi) st[ki][qi] = zero4;

        __builtin_amdgcn_s_setprio(1);
        #pragma unroll
        for (int kc = 0; kc < 2; ++kc)
          #pragma unroll
          for (int ki = 0; ki < 2; ++ki)
            #pragma unroll
            for (int qi = 0; qi < 2; ++qi)
              st[ki][qi] = __builtin_amdgcn_mfma_f32_16x16x32_bf16(
                  kf[ki][kc].v, qf[qi][kc].v, st[ki][qi], 0, 0, 0);
        __builtin_amdgcn_s_setprio(0);

        #pragma unroll
        for (int ki = 0; ki < 2; ++ki)
          #pragma unroll
          for (int qi = 0; qi < 2; ++qi) {
            f32x4_t s = st[ki][qi];
            #pragma unroll
            for (int r = 0; r < 4; ++r) {
              float pr = __builtin_amdgcn_exp2f(s[r]);
              s[r] = pr;
              lsum[qi] += pr;
            }
            st[ki][qi] = s;
          }

        Frag vf[4];
        #pragma unroll
        for (int di = 0; di < 4; ++di) {
          const unsigned char* vp = smem + VT_BASE + (di * 16 + l15) * (VSTR * 2)
                                    + kt * 64 + 8 * g;
          vf[di].d[0] = *(const uint2*)(vp);
          vf[di].d[1] = *(const uint2*)(vp + 32);
        }

        __builtin_amdgcn_s_setprio(1);
        #pragma unroll
        for (int qi = 0; qi < 2; ++qi) {
          Frag pb;
          #pragma unroll
          for (int r = 0; r < 4; ++r) {
            pb.u[r]     = f2bf(st[0][qi][r]);
            pb.u[4 + r] = f2bf(st[1][qi][r]);
          }
          #pragma unroll
          for (int di = 0; di < 4; ++di)
            ot[di][qi] = __builtin_amdgcn_mfma_f32_16x16x32_bf16(
                vf[di].v, pb.v, ot[di][qi], 0, 0, 0);
        }
        __builtin_amdgcn_s_setprio(0);
      }

      if (c < 3) { writeC(c + 1); BARRIER_NODRAIN(); }
    }

    if (p == 0) buildQF();   // pair-1 Q frags; qin dead afterwards

    // ---- softmax denominators ----
    float rl[2];
    #pragma unroll
    for (int qi = 0; qi < 2; ++qi) {
      float s = lsum[qi];
      s += __shfl_xor(s, 16, 64);
      s += __shfl_xor(s, 32, 64);
      rl[qi] = 1.0f / s;
    }

    // ---- LePE conv from Vt LDS (lane = channel), wave rows wave*4..+3 ----
    float wgt[9];
    {
      const float* wp = lw + (size_t)(head * HDV + lane) * 9;
      #pragma unroll
      for (int i = 0; i < 9; ++i) wgt[i] = wp[i];
    }
    const float bias = lb[head * HDV + lane];
    const int yb = wave * 4;

    float rm[8], rc[8], rp2[8], lout[32];
    auto loadrow = [&](int y, float* dst) {
      if ((unsigned)y < 64u) {
        const unsigned char* pp = smem + VT_BASE + lane * (VSTR * 2) + y * 16;
        unsigned a0 = *(const unsigned*)(pp);
        unsigned a1 = *(const unsigned*)(pp + 4);
        unsigned a2 = *(const unsigned*)(pp + 8);
        unsigned a3 = *(const unsigned*)(pp + 12);
        dst[0] = bf2f(a0 & 0xffffu); dst[1] = bf2f(a0 >> 16);
        dst[2] = bf2f(a1 & 0xffffu); dst[3] = bf2f(a1 >> 16);
        dst[4] = bf2f(a2 & 0xffffu); dst[5] = bf2f(a2 >> 16);
        dst[6] = bf2f(a3 & 0xffffu); dst[7] = bf2f(a3 >> 16);
      } else {
        #pragma unroll
        for (int x = 0; x < 8; ++x) dst[x] = 0.f;
      }
    };
    loadrow(yb - 1, rm);
    loadrow(yb, rc);
    #pragma unroll
    for (int yy = 0; yy < 4; ++yy) {
      loadrow(yb + yy + 1, rp2);
      #pragma unroll
      for (int x = 0; x < 8; ++x) {
        float acc = bias;
        if (x > 0) acc += rm[x-1]*wgt[0] + rc[x-1]*wgt[3] + rp2[x-1]*wgt[6];
        acc += rm[x]*wgt[1] + rc[x]*wgt[4] + rp2[x]*wgt[7];
        if (x < 7) acc += rm[x+1]*wgt[2] + rc[x+1]*wgt[5] + rp2[x+1]*wgt[8];
        lout[yy * 8 + x] = acc;
      }
      #pragma unroll
      for (int x = 0; x < 8; ++x) { rm[x] = rc[x]; rc[x] = rp2[x]; }
    }

    BARRIER_NODRAIN();   // all waves done reading Vt (bounce clobbers Vt ch 0-3)

    if (p == 0) issueC(headbase + 1, 0);   // pair-1 chunk0 in flight over epilogue

    unsigned char* bp = smem + wave * 4352;   // [32 tok][68 ch] bf16 per wave
    #pragma unroll
    for (int t = 0; t < 32; ++t)
      *(unsigned short*)(bp + t * 136 + 2 * lane) = f2bf(lout[t]);
    BARRIER_NODRAIN();

    // ---- normalize, add LePE, store ----
    #pragma unroll
    for (int qi = 0; qi < 2; ++qi) {
      const float rlq = rl[qi];
      const int tl = qi * 16 + l15;
      float* op = out + (size_t)grow(qbase + tl) * DIMV + head * HDV;
      #pragma unroll
      for (int di = 0; di < 4; ++di) {
        uint2 lv = *(const uint2*)(bp + tl * 136 + di * 32 + 8 * g);
        float4 o;
        o.x = ot[di][qi][0] * rlq + bf2f(lv.x & 0xffffu);
        o.y = ot[di][qi][1] * rlq + bf2f(lv.x >> 16);
        o.z = ot[di][qi][2] * rlq + bf2f(lv.y & 0xffffu);
        o.w = ot[di][qi][3] * rlq + bf2f(lv.y >> 16);
        *(float4*)(op + di * 16 + 4 * g) = o;
      }
    }

    if (p == 0) {
      BARRIER_NODRAIN();   // all bounce reads done before chunk0 overwrites
      writeC(0);           // pair-1 chunk0 into recycled LDS
      BARRIER_NODRAIN();   // publish
    }
  }
}

extern "C" void kernel_launch(void* const* d_in, const int* in_sizes, int n_in,
                              void* d_out, int out_size, void* d_ws, size_t ws_size,
                              hipStream_t stream) {
  const float* qkv = (const float*)d_in[0];
  const float* lw  = (const float*)d_in[1];
  const float* lb  = (const float*)d_in[2];
  float* out = (float*)d_out;
  (void)in_sizes; (void)n_in; (void)out_size; (void)d_ws; (void)ws_size;

  dim3 grid(256);    // 64 win x 4 head-pairs; 2 heads per block
  dim3 block(1024);  // 16 waves x 32 queries
  hipLaunchKernelGGL(lepe_attn_kernel, grid, block, 0, stream, qkv, lw, lb, out);
}

// Round 8
// 85.711 us; speedup vs baseline: 5.4874x; 5.4874x over previous
//
#include <hip/hip_runtime.h>
#include <hip/hip_bf16.h>

#define DIMV 512
#define HDV  64
#define VSTR 524                          // shorts per Vt row (1048 B)
#define VT_BASE 65536                     // K region: 16 tiles x 4096 B, fragment-ordered
#define SMEM_B (VT_BASE + 64 * VSTR * 2)  // 132,608 B

typedef __bf16 bf16x8_t __attribute__((ext_vector_type(8)));
typedef float f32x4_t __attribute__((ext_vector_type(4)));

union Frag { bf16x8_t v; unsigned short u[8]; unsigned int w[4]; uint2 d[2]; uint4 q; };

static __device__ __forceinline__ unsigned short f2bf(float f) {
  return __builtin_bit_cast(unsigned short, (__bf16)f);
}
static __device__ __forceinline__ float bf2f(unsigned int h) {
  return __builtin_bit_cast(float, h << 16);
}
static __device__ __forceinline__ uint2 pack4(const float4 f) {
  uint2 r;
  r.x = (unsigned)f2bf(f.x) | ((unsigned)f2bf(f.y) << 16);
  r.y = (unsigned)f2bf(f.z) | ((unsigned)f2bf(f.w) << 16);
  return r;
}

// Barrier that does NOT drain vmcnt: LDS visibility only; global loads into
// private carrier regs stay in flight across it.
#define BARRIER_NODRAIN() asm volatile("s_waitcnt lgkmcnt(0)\n\ts_barrier" ::: "memory")

__global__ __launch_bounds__(1024, 4)
void lepe_attn_kernel(const float* __restrict__ qkv,
                      const float* __restrict__ lw,
                      const float* __restrict__ lb,
                      float* __restrict__ out)
{
  __shared__ __align__(16) unsigned char smem[SMEM_B];

  const int wb   = blockIdx.x;        // 256 blocks; each does 2 heads of one window
  const int win  = wb >> 2;
  const int bat  = win >> 3;
  const int nw   = win & 7;
  const int headbase = (wb & 3) << 1;

  const int tid  = threadIdx.x;
  const int wave = tid >> 6, lane = tid & 63;
  const int l15  = lane & 15, g = lane >> 4;

  const float* qptr = qkv;
  const float* kptr = qkv + 16777216;
  const float* vptr = qkv + 33554432;
  const int rowbase = bat * 4096;

  auto grow = [&](int tok) -> int {   // window token -> global row
    return rowbase + ((tok >> 3) << 6) + (nw << 3) + (tok & 7);
  };

  // ---- staging mapping: token s_t (0..63 within group), channel quad s_c ----
  const int s_t = tid >> 4;
  const int s_c = (tid & 15) * 4;
  const size_t TSTRIDE = 262144;      // floats between consecutive 64-token groups
  const size_t base_st = (size_t)grow(s_t) * DIMV + s_c;

  // K fragment-ordered write position: tile block 4096 B = [ki 2][kc 2][lane 64][16 B]
  const int lr    = s_t & 31;                    // row within tile
  const int tb0   = (s_t >> 5) * 4096;           // which tile within a 64-token group
  const int kfrag = (lr >> 4) * 2048 + (s_c >> 5) * 1024
                  + ((lr & 15) + 16 * ((s_c >> 3) & 3)) * 16 + (s_c & 7) * 2;

  unsigned short* vt = (unsigned short*)(smem + VT_BASE);

  float4 ck0, ck1, cv0, cv1;   // chunk carrier (2 groups K + 2 groups V)
  float4 qin[8];               // Q staging (transient)

  auto issueC = [&](int head, int c) {
    const float* kgp = kptr + base_st + head * HDV;
    const float* vgp = vptr + base_st + head * HDV;
    ck0 = *(const float4*)(kgp + (size_t)(2 * c) * TSTRIDE);
    ck1 = *(const float4*)(kgp + (size_t)(2 * c + 1) * TSTRIDE);
    cv0 = *(const float4*)(vgp + (size_t)(2 * c) * TSTRIDE);
    cv1 = *(const float4*)(vgp + (size_t)(2 * c + 1) * TSTRIDE);
  };
  auto writeC = [&](int c) {
    *(uint2*)(smem + c * 16384 + tb0 + kfrag)        = pack4(ck0);
    *(uint2*)(smem + c * 16384 + 8192 + tb0 + kfrag) = pack4(ck1);
    int t0 = s_t + 128 * c;
    vt[(s_c + 0) * VSTR + t0] = f2bf(cv0.x);
    vt[(s_c + 1) * VSTR + t0] = f2bf(cv0.y);
    vt[(s_c + 2) * VSTR + t0] = f2bf(cv0.z);
    vt[(s_c + 3) * VSTR + t0] = f2bf(cv0.w);
    int t1 = t0 + 64;
    vt[(s_c + 0) * VSTR + t1] = f2bf(cv1.x);
    vt[(s_c + 1) * VSTR + t1] = f2bf(cv1.y);
    vt[(s_c + 2) * VSTR + t1] = f2bf(cv1.z);
    vt[(s_c + 3) * VSTR + t1] = f2bf(cv1.w);
  };

  const float QSC = 0.1803368801f;   // 0.125 * log2(e): P = exp2(S)
  const int qbase = wave * 32;
  size_t qoff[2];
  qoff[0] = (size_t)grow(qbase + l15) * DIMV;
  qoff[1] = (size_t)grow(qbase + 16 + l15) * DIMV;

  Frag qf[2][2];
  auto issueQ = [&](int head) {
    #pragma unroll
    for (int qi = 0; qi < 2; ++qi) {
      const float* qp = qptr + qoff[qi] + head * HDV;
      #pragma unroll
      for (int kc = 0; kc < 2; ++kc) {
        qin[qi * 4 + kc * 2 + 0] = *(const float4*)(qp + kc * 32 + 8 * g);
        qin[qi * 4 + kc * 2 + 1] = *(const float4*)(qp + kc * 32 + 8 * g + 4);
      }
    }
  };
  auto buildQF = [&]() {
    #pragma unroll
    for (int qi = 0; qi < 2; ++qi)
      #pragma unroll
      for (int kc = 0; kc < 2; ++kc) {
        const float4 f0 = qin[qi * 4 + kc * 2 + 0];
        const float4 f1 = qin[qi * 4 + kc * 2 + 1];
        qf[qi][kc].u[0] = f2bf(f0.x * QSC); qf[qi][kc].u[1] = f2bf(f0.y * QSC);
        qf[qi][kc].u[2] = f2bf(f0.z * QSC); qf[qi][kc].u[3] = f2bf(f0.w * QSC);
        qf[qi][kc].u[4] = f2bf(f1.x * QSC); qf[qi][kc].u[5] = f2bf(f1.y * QSC);
        qf[qi][kc].u[6] = f2bf(f1.z * QSC); qf[qi][kc].u[7] = f2bf(f1.w * QSC);
      }
  };

  // ---- prologue: pair-0 chunk0 + Q; write; publish ----
  issueC(headbase, 0);
  issueQ(headbase);
  writeC(0);
  buildQF();
  __syncthreads();

  const f32x4_t zero4 = {0.f, 0.f, 0.f, 0.f};
  const unsigned char* kfb = smem + lane * 16;   // fragment read base

  #pragma unroll
  for (int p = 0; p < 2; ++p) {
    const int head = headbase + p;

    f32x4_t ot[4][2];
    #pragma unroll
    for (int di = 0; di < 4; ++di)
      #pragma unroll
      for (int qi = 0; qi < 2; ++qi) ot[di][qi] = zero4;
    float lsum[2] = {0.f, 0.f};

    // ---- main loop: 4 chunks x 4 tiles of 32 keys; 1-ahead pipeline ----
    #pragma unroll
    for (int c = 0; c < 4; ++c) {
      if (c < 3) issueC(head, c + 1);

      #pragma unroll
      for (int t4 = 0; t4 < 4; ++t4) {
        const int kt = c * 4 + t4;

        Frag kf[2][2];
        #pragma unroll
        for (int ki = 0; ki < 2; ++ki)
          #pragma unroll
          for (int kc = 0; kc < 2; ++kc)
            kf[ki][kc].q = *(const uint4*)(kfb + kt * 4096 + ki * 2048 + kc * 1024);

        f32x4_t st[2][2];
        #pragma unroll
        for (int ki = 0; ki < 2; ++ki)
          #pragma unroll
          for (int qi = 0; qi < 2; ++qi) st[ki][qi] = zero4;

        __builtin_amdgcn_s_setprio(1);
        #pragma unroll
        for (int kc = 0; kc < 2; ++kc)
          #pragma unroll
          for (int ki = 0; ki < 2; ++ki)
            #pragma unroll
            for (int qi = 0; qi < 2; ++qi)
              st[ki][qi] = __builtin_amdgcn_mfma_f32_16x16x32_bf16(
                  kf[ki][kc].v, qf[qi][kc].v, st[ki][qi], 0, 0, 0);
        __builtin_amdgcn_s_setprio(0);

        #pragma unroll
        for (int ki = 0; ki < 2; ++ki)
          #pragma unroll
          for (int qi = 0; qi < 2; ++qi) {
            f32x4_t s = st[ki][qi];
            #pragma unroll
            for (int r = 0; r < 4; ++r) {
              float pr = __builtin_amdgcn_exp2f(s[r]);
              s[r] = pr;
              lsum[qi] += pr;
            }
            st[ki][qi] = s;
          }

        Frag vf[4];
        #pragma unroll
        for (int di = 0; di < 4; ++di) {
          const unsigned char* vp = smem + VT_BASE + (di * 16 + l15) * (VSTR * 2)
                                    + kt * 64 + 8 * g;
          vf[di].d[0] = *(const uint2*)(vp);
          vf[di].d[1] = *(const uint2*)(vp + 32);
        }

        __builtin_amdgcn_s_setprio(1);
        #pragma unroll
        for (int qi = 0; qi < 2; ++qi) {
          Frag pb;
          #pragma unroll
          for (int r = 0; r < 4; ++r) {
            pb.u[r]     = f2bf(st[0][qi][r]);
            pb.u[4 + r] = f2bf(st[1][qi][r]);
          }
          #pragma unroll
          for (int di = 0; di < 4; ++di)
            ot[di][qi] = __builtin_amdgcn_mfma_f32_16x16x32_bf16(
                vf[di].v, pb.v, ot[di][qi], 0, 0, 0);
        }
        __builtin_amdgcn_s_setprio(0);
      }

      if (c < 3) { writeC(c + 1); BARRIER_NODRAIN(); }
    }

    // ---- softmax denominators ----
    float rl[2];
    #pragma unroll
    for (int qi = 0; qi < 2; ++qi) {
      float s = lsum[qi];
      s += __shfl_xor(s, 16, 64);
      s += __shfl_xor(s, 32, 64);
      rl[qi] = 1.0f / s;
    }

    // ---- LePE conv from Vt LDS (lane = channel), wave rows wave*4..+3 ----
    float lout[32];
    {
      float wgt[9];
      const float* wp = lw + (size_t)(head * HDV + lane) * 9;
      #pragma unroll
      for (int i = 0; i < 9; ++i) wgt[i] = wp[i];
      const float bias = lb[head * HDV + lane];
      const int yb = wave * 4;

      float rm[8], rc[8], rp2[8];
      auto loadrow = [&](int y, float* dst) {
        if ((unsigned)y < 64u) {
          const unsigned char* pp = smem + VT_BASE + lane * (VSTR * 2) + y * 16;
          unsigned a0 = *(const unsigned*)(pp);
          unsigned a1 = *(const unsigned*)(pp + 4);
          unsigned a2 = *(const unsigned*)(pp + 8);
          unsigned a3 = *(const unsigned*)(pp + 12);
          dst[0] = bf2f(a0 & 0xffffu); dst[1] = bf2f(a0 >> 16);
          dst[2] = bf2f(a1 & 0xffffu); dst[3] = bf2f(a1 >> 16);
          dst[4] = bf2f(a2 & 0xffffu); dst[5] = bf2f(a2 >> 16);
          dst[6] = bf2f(a3 & 0xffffu); dst[7] = bf2f(a3 >> 16);
        } else {
          #pragma unroll
          for (int x = 0; x < 8; ++x) dst[x] = 0.f;
        }
      };
      loadrow(yb - 1, rm);
      loadrow(yb, rc);
      #pragma unroll
      for (int yy = 0; yy < 4; ++yy) {
        loadrow(yb + yy + 1, rp2);
        #pragma unroll
        for (int x = 0; x < 8; ++x) {
          float acc = bias;
          if (x > 0) acc += rm[x-1]*wgt[0] + rc[x-1]*wgt[3] + rp2[x-1]*wgt[6];
          acc += rm[x]*wgt[1] + rc[x]*wgt[4] + rp2[x]*wgt[7];
          if (x < 7) acc += rm[x+1]*wgt[2] + rc[x+1]*wgt[5] + rp2[x+1]*wgt[8];
          lout[yy * 8 + x] = acc;
        }
        #pragma unroll
        for (int x = 0; x < 8; ++x) { rm[x] = rc[x]; rc[x] = rp2[x]; }
      }
    }

    BARRIER_NODRAIN();   // all LePE reads of Vt done before bounce clobbers it

    unsigned char* bp = smem + wave * 4352;   // [32 tok][68 ch] bf16 per wave
    #pragma unroll
    for (int t = 0; t < 32; ++t)
      *(unsigned short*)(bp + t * 136 + 2 * lane) = f2bf(lout[t]);

    if (p == 0) issueC(headbase + 1, 0);   // lout dead; only 16 carrier regs live

    // ---- normalize, add LePE, store (reads own wave's bounce region) ----
    #pragma unroll
    for (int qi = 0; qi < 2; ++qi) {
      const float rlq = rl[qi];
      const int tl = qi * 16 + l15;
      float* op = out + (size_t)grow(qbase + tl) * DIMV + head * HDV;
      #pragma unroll
      for (int di = 0; di < 4; ++di) {
        uint2 lv = *(const uint2*)(bp + tl * 136 + di * 32 + 8 * g);
        float4 o;
        o.x = ot[di][qi][0] * rlq + bf2f(lv.x & 0xffffu);
        o.y = ot[di][qi][1] * rlq + bf2f(lv.x >> 16);
        o.z = ot[di][qi][2] * rlq + bf2f(lv.y & 0xffffu);
        o.w = ot[di][qi][3] * rlq + bf2f(lv.y >> 16);
        *(float4*)(op + di * 16 + 4 * g) = o;
      }
    }

    if (p == 0) {
      BARRIER_NODRAIN();        // all bounce reads done before chunk0 overwrites
      writeC(0);                // pair-1 chunk0 (K tiles 0-3 + Vt cols 0-127)
      issueQ(headbase + 1);     // direct load; exposed once (~600 cy)
      buildQF();
      BARRIER_NODRAIN();        // publish chunk0
    }
  }
}

extern "C" void kernel_launch(void* const* d_in, const int* in_sizes, int n_in,
                              void* d_out, int out_size, void* d_ws, size_t ws_size,
                              hipStream_t stream) {
  const float* qkv = (const float*)d_in[0];
  const float* lw  = (const float*)d_in[1];
  const float* lb  = (const float*)d_in[2];
  float* out = (float*)d_out;
  (void)in_sizes; (void)n_in; (void)out_size; (void)d_ws; (void)ws_size;

  dim3 grid(256);    // 64 win x 4 head-pairs; 2 heads per block, 1 block per CU
  dim3 block(1024);  // 16 waves x 32 queries
  hipLaunchKernelGGL(lepe_attn_kernel, grid, block, 0, stream, qkv, lw, lb, out);
}

// Round 9
// 83.929 us; speedup vs baseline: 5.6039x; 1.0212x over previous
//
#include <hip/hip_runtime.h>
#include <hip/hip_bf16.h>

#define DIMV 512
#define HDV  64
#define KRING_B 16384                 // 2 slots x 8 KB (chunk = 64 keys = 2 frag tiles)
#define VT_BASE KRING_B               // V^T: 64 rows x 1024 B, XOR-swizzled, padless
#define SMEM_B (VT_BASE + 65536)      // 81,920 B -> 2 blocks/CU (160 KB pool exactly)

typedef __bf16 bf16x8_t __attribute__((ext_vector_type(8)));
typedef float f32x4_t __attribute__((ext_vector_type(4)));

union Frag { bf16x8_t v; unsigned short u[8]; unsigned int w[4]; uint2 d[2]; uint4 q; };

static __device__ __forceinline__ unsigned short f2bf(float f) {
  return __builtin_bit_cast(unsigned short, (__bf16)f);
}
static __device__ __forceinline__ float bf2f(unsigned int h) {
  return __builtin_bit_cast(float, h << 16);
}
static __device__ __forceinline__ uint2 pack4(const float4 f) {
  uint2 r;
  r.x = (unsigned)f2bf(f.x) | ((unsigned)f2bf(f.y) << 16);
  r.y = (unsigned)f2bf(f.z) | ((unsigned)f2bf(f.w) << 16);
  return r;
}

// LDS-visibility-only barrier: vmcnt NOT drained (carrier loads stay in flight).
#define BARRIER_NODRAIN() asm volatile("s_waitcnt lgkmcnt(0)\n\ts_barrier" ::: "memory")

__global__ __launch_bounds__(1024, 4)
void lepe_attn_kernel(const float* __restrict__ qkv,
                      const float* __restrict__ lw,
                      const float* __restrict__ lb,
                      float* __restrict__ out)
{
  __shared__ __align__(16) unsigned char smem[SMEM_B];

  const int head = blockIdx.x & 7;
  const int win  = blockIdx.x >> 3;
  const int bat  = win >> 3;
  const int nw   = win & 7;

  const int tid  = threadIdx.x;
  const int wave = tid >> 6, lane = tid & 63;
  const int l15  = lane & 15, g = lane >> 4;

  const float* qptr = qkv;
  const float* kptr = qkv + 16777216;
  const float* vptr = qkv + 33554432;
  const int rowbase = bat * 4096;

  auto grow = [&](int tok) -> int {
    return rowbase + ((tok >> 3) << 6) + (nw << 3) + (tok & 7);
  };

  // ---- staging mapping: key/token s_t (0..63 in group), channel quad s_c ----
  const int s_t = tid >> 4;
  const int s_c = (tid & 15) * 4;
  const size_t GSTRIDE = 262144;            // floats between 64-token groups
  const float* kg = kptr + (size_t)grow(s_t) * DIMV + head * HDV + s_c;
  const float* vg = vptr + (size_t)grow(s_t) * DIMV + head * HDV + s_c;

  // K fragment write byte (within 8 KB chunk slot): [tile][ki][kc][lane][16B]
  const int lr  = s_t & 31;
  const int kwb = (s_t >> 5) * 4096 + (lr >> 4) * 2048 + (s_c >> 5) * 1024
                + ((lr & 15) + 16 * ((s_c >> 3) & 3)) * 16 + (s_c & 7) * 2;

  float4 kc4;   // 1-chunk K carrier (4 VGPR)
  auto issueK = [&](int c) { kc4 = *(const float4*)(kg + (size_t)c * GSTRIDE); };
  auto writeK = [&](int c) {
    *(uint2*)(smem + (c & 1) * 8192 + kwb) = pack4(kc4);
  };

  // ---- prologue: K chunk0 + all V + Q issued; convert; publish ----
  issueK(0);
  float4 vin[8];
  #pragma unroll
  for (int j = 0; j < 8; ++j) vin[j] = *(const float4*)(vg + (size_t)j * GSTRIDE);

  const float QSC = 0.1803368801f;          // 0.125 * log2(e): P = exp2(S)
  const int qbase = wave * 32;
  float4 qin[8];
  #pragma unroll
  for (int qi = 0; qi < 2; ++qi) {
    const float* qp = qptr + (size_t)grow(qbase + qi * 16 + l15) * DIMV + head * HDV;
    #pragma unroll
    for (int kc = 0; kc < 2; ++kc) {
      qin[qi * 4 + kc * 2 + 0] = *(const float4*)(qp + kc * 32 + 8 * g);
      qin[qi * 4 + kc * 2 + 1] = *(const float4*)(qp + kc * 32 + 8 * g + 4);
    }
  }

  writeK(0);
  // V^T write: element (d, t) at d*1024 + (2t ^ ((d&7)<<4))
  #pragma unroll
  for (int j = 0; j < 8; ++j) {
    const int t2 = 2 * (j * 64 + s_t);
    float fv[4] = {vin[j].x, vin[j].y, vin[j].z, vin[j].w};
    #pragma unroll
    for (int i = 0; i < 4; ++i) {
      const int d = s_c + i;
      *(unsigned short*)(smem + VT_BASE + d * 1024 + (t2 ^ ((d & 7) << 4))) = f2bf(fv[i]);
    }
  }

  Frag qf[2][2];
  #pragma unroll
  for (int qi = 0; qi < 2; ++qi)
    #pragma unroll
    for (int kc = 0; kc < 2; ++kc) {
      const float4 f0 = qin[qi * 4 + kc * 2 + 0];
      const float4 f1 = qin[qi * 4 + kc * 2 + 1];
      qf[qi][kc].u[0] = f2bf(f0.x * QSC); qf[qi][kc].u[1] = f2bf(f0.y * QSC);
      qf[qi][kc].u[2] = f2bf(f0.z * QSC); qf[qi][kc].u[3] = f2bf(f0.w * QSC);
      qf[qi][kc].u[4] = f2bf(f1.x * QSC); qf[qi][kc].u[5] = f2bf(f1.y * QSC);
      qf[qi][kc].u[6] = f2bf(f1.z * QSC); qf[qi][kc].u[7] = f2bf(f1.w * QSC);
    }

  __syncthreads();

  const f32x4_t zero4 = {0.f, 0.f, 0.f, 0.f};
  f32x4_t ot[4][2];
  #pragma unroll
  for (int di = 0; di < 4; ++di)
    #pragma unroll
    for (int qi = 0; qi < 2; ++qi) ot[di][qi] = zero4;
  float lsum[2] = {0.f, 0.f};

  const int vswz = (l15 & 7) << 4;

  // ---- main loop: 8 chunks x 2 tiles of 32 keys; 1-ahead K pipeline ----
  for (int c = 0; c < 8; ++c) {
    if (c < 7) issueK(c + 1);

    #pragma unroll
    for (int t2i = 0; t2i < 2; ++t2i) {
      const int kt = c * 2 + t2i;
      const unsigned char* kbase = smem + (c & 1) * 8192 + t2i * 4096 + lane * 16;

      Frag kf[2][2];
      #pragma unroll
      for (int ki = 0; ki < 2; ++ki)
        #pragma unroll
        for (int kc = 0; kc < 2; ++kc)
          kf[ki][kc].q = *(const uint4*)(kbase + ki * 2048 + kc * 1024);

      f32x4_t st[2][2];
      #pragma unroll
      for (int ki = 0; ki < 2; ++ki)
        #pragma unroll
        for (int qi = 0; qi < 2; ++qi) st[ki][qi] = zero4;

      __builtin_amdgcn_s_setprio(1);
      #pragma unroll
      for (int kc = 0; kc < 2; ++kc)
        #pragma unroll
        for (int ki = 0; ki < 2; ++ki)
          #pragma unroll
          for (int qi = 0; qi < 2; ++qi)
            st[ki][qi] = __builtin_amdgcn_mfma_f32_16x16x32_bf16(
                kf[ki][kc].v, qf[qi][kc].v, st[ki][qi], 0, 0, 0);
      __builtin_amdgcn_s_setprio(0);

      #pragma unroll
      for (int ki = 0; ki < 2; ++ki)
        #pragma unroll
        for (int qi = 0; qi < 2; ++qi) {
          f32x4_t s = st[ki][qi];
          #pragma unroll
          for (int r = 0; r < 4; ++r) {
            float pr = __builtin_amdgcn_exp2f(s[r]);
            s[r] = pr;
            lsum[qi] += pr;
          }
          st[ki][qi] = s;
        }

      Frag vf[4];
      #pragma unroll
      for (int di = 0; di < 4; ++di) {
        const unsigned char* vrow = smem + VT_BASE + (di * 16 + l15) * 1024;
        vf[di].d[0] = *(const uint2*)(vrow + ((kt * 64 + 8 * g) ^ vswz));
        vf[di].d[1] = *(const uint2*)(vrow + ((kt * 64 + 32 + 8 * g) ^ vswz));
      }

      __builtin_amdgcn_s_setprio(1);
      #pragma unroll
      for (int qi = 0; qi < 2; ++qi) {
        Frag pb;
        #pragma unroll
        for (int r = 0; r < 4; ++r) {
          pb.u[r]     = f2bf(st[0][qi][r]);
          pb.u[4 + r] = f2bf(st[1][qi][r]);
        }
        #pragma unroll
        for (int di = 0; di < 4; ++di)
          ot[di][qi] = __builtin_amdgcn_mfma_f32_16x16x32_bf16(
              vf[di].v, pb.v, ot[di][qi], 0, 0, 0);
      }
      __builtin_amdgcn_s_setprio(0);
    }

    if (c < 7) { writeK(c + 1); BARRIER_NODRAIN(); }
  }

  // ---- softmax denominators ----
  float rl[2];
  #pragma unroll
  for (int qi = 0; qi < 2; ++qi) {
    float s = lsum[qi];
    s += __shfl_xor(s, 16, 64);
    s += __shfl_xor(s, 32, 64);
    rl[qi] = 1.0f / s;
  }

  // ---- LePE conv from swizzled V^T (lane = channel), wave rows wave*4..+3 ----
  float lout[32];
  {
    float wgt[9];
    const float* wp = lw + (size_t)(head * HDV + lane) * 9;
    #pragma unroll
    for (int i = 0; i < 9; ++i) wgt[i] = wp[i];
    const float bias = lb[head * HDV + lane];
    const int yb = wave * 4;
    const unsigned char* vrow = smem + VT_BASE + lane * 1024;
    const int lsw = (lane & 7) << 4;

    float rm[8], rc[8], rp2[8];
    auto loadrow = [&](int y, float* dst) {
      if ((unsigned)y < 64u) {
        uint4 a = *(const uint4*)(vrow + ((y * 16) ^ lsw));
        dst[0] = bf2f(a.x & 0xffffu); dst[1] = bf2f(a.x >> 16);
        dst[2] = bf2f(a.y & 0xffffu); dst[3] = bf2f(a.y >> 16);
        dst[4] = bf2f(a.z & 0xffffu); dst[5] = bf2f(a.z >> 16);
        dst[6] = bf2f(a.w & 0xffffu); dst[7] = bf2f(a.w >> 16);
      } else {
        #pragma unroll
        for (int x = 0; x < 8; ++x) dst[x] = 0.f;
      }
    };
    loadrow(yb - 1, rm);
    loadrow(yb, rc);
    #pragma unroll
    for (int yy = 0; yy < 4; ++yy) {
      loadrow(yb + yy + 1, rp2);
      #pragma unroll
      for (int x = 0; x < 8; ++x) {
        float acc = bias;
        if (x > 0) acc += rm[x-1]*wgt[0] + rc[x-1]*wgt[3] + rp2[x-1]*wgt[6];
        acc += rm[x]*wgt[1] + rc[x]*wgt[4] + rp2[x]*wgt[7];
        if (x < 7) acc += rm[x+1]*wgt[2] + rc[x+1]*wgt[5] + rp2[x+1]*wgt[8];
        lout[yy * 8 + x] = acc;
      }
      #pragma unroll
      for (int x = 0; x < 8; ++x) { rm[x] = rc[x]; rc[x] = rp2[x]; }
    }
  }

  BARRIER_NODRAIN();   // all PV + LePE reads of V^T done before bounce clobbers it

  // ---- bounce LePE into dead V region: [tok][128 B row, swizzled by tok] ----
  #pragma unroll
  for (int t = 0; t < 32; ++t) {
    const int tok = qbase + t;
    *(unsigned short*)(smem + VT_BASE + tok * 128 + ((2 * lane) ^ ((tok & 7) << 4)))
        = f2bf(lout[t]);
  }
  BARRIER_NODRAIN();

  // ---- normalize, add LePE, store ----
  #pragma unroll
  for (int qi = 0; qi < 2; ++qi) {
    const float rlq = rl[qi];
    const int tok = qbase + qi * 16 + l15;
    const unsigned char* brow = smem + VT_BASE + tok * 128;
    const int bsw = (l15 & 7) << 4;
    float* op = out + (size_t)grow(tok) * DIMV + head * HDV;
    #pragma unroll
    for (int di = 0; di < 4; ++di) {
      uint2 lv = *(const uint2*)(brow + ((di * 32 + 8 * g) ^ bsw));
      float4 o;
      o.x = ot[di][qi][0] * rlq + bf2f(lv.x & 0xffffu);
      o.y = ot[di][qi][1] * rlq + bf2f(lv.x >> 16);
      o.z = ot[di][qi][2] * rlq + bf2f(lv.y & 0xffffu);
      o.w = ot[di][qi][3] * rlq + bf2f(lv.y >> 16);
      *(float4*)(op + di * 16 + 4 * g) = o;
    }
  }
}

extern "C" void kernel_launch(void* const* d_in, const int* in_sizes, int n_in,
                              void* d_out, int out_size, void* d_ws, size_t ws_size,
                              hipStream_t stream) {
  const float* qkv = (const float*)d_in[0];
  const float* lw  = (const float*)d_in[1];
  const float* lb  = (const float*)d_in[2];
  float* out = (float*)d_out;
  (void)in_sizes; (void)n_in; (void)out_size; (void)d_ws; (void)ws_size;

  dim3 grid(512);    // 64 win x 8 heads; 80 KB LDS -> 2 blocks/CU, 1 round
  dim3 block(1024);  // 16 waves x 32 queries
  hipLaunchKernelGGL(lepe_attn_kernel, grid, block, 0, stream, qkv, lw, lb, out);
}